// Round 3
// baseline (370.951 us; speedup 1.0000x reference)
//
#include <hip/hip_runtime.h>
#include <math.h>

// Problem constants (from reference setup_inputs)
constexpr int B = 1024;   // batch
constexpr int A = 64;     // answers per query (== one wavefront)
constexpr int D = 1024;   // embedding dim
constexpr float EPS = 1e-8f;

__device__ __forceinline__ float wave_reduce_sum(float v) {
    #pragma unroll
    for (int off = 32; off > 0; off >>= 1) v += __shfl_xor(v, off, 64);
    return v;
}
__device__ __forceinline__ float wave_reduce_max(float v) {
    #pragma unroll
    for (int off = 32; off > 0; off >>= 1) v = fmaxf(v, __shfl_xor(v, off, 64));
    return v;
}

// ---------------------------------------------------------------------------
// Fused kernel: one block per batch row.
// Phase 1: 4 waves x 16 answers each — coalesced float4 dot products,
//          wave-shuffle reduce, sims to LDS.
// Phase 2: wave 0 does softmax/KL/ranks/DCG for the row (A=64 == wave).
// __launch_bounds__(256,4): 128-VGPR cap — no spill risk, 16 waves/CU,
// ~128 KB of loads in flight per CU (need ~9.2 KB to hide 900-cyc HBM).
// ---------------------------------------------------------------------------
__global__ __launch_bounds__(256, 4) void rank_fused(
    const float* __restrict__ q,       // [B, D]
    const float* __restrict__ emb,     // [B, A, D]
    const float* __restrict__ scores,  // [B, A]
    float* __restrict__ kl_out,        // [B]
    float* __restrict__ nd_out)        // [B]
{
    const int b    = blockIdx.x;
    const int tid  = threadIdx.x;
    const int wave = tid >> 6;
    const int lane = tid & 63;

    __shared__ float sim_s[A];

    // q[b] fragment: lane covers d = 4*lane + 256*it, it = 0..3 (16 floats)
    const float4* q4 = reinterpret_cast<const float4*>(q + (size_t)b * D);
    const float4 qv0 = q4[lane];
    const float4 qv1 = q4[lane + 64];
    const float4 qv2 = q4[lane + 128];
    const float4 qv3 = q4[lane + 192];

    const int a0 = wave * 16;
    #pragma unroll 2
    for (int ai = 0; ai < 16; ++ai) {
        const int a = a0 + ai;
        const float4* e4 = reinterpret_cast<const float4*>(
            emb + ((size_t)b * A + a) * D);
        const float4 e0 = e4[lane];
        const float4 e1 = e4[lane + 64];
        const float4 e2 = e4[lane + 128];
        const float4 e3 = e4[lane + 192];
        // 4 independent partial sums -> short dependence chains
        float s0 = qv0.x*e0.x + qv0.y*e0.y + qv0.z*e0.z + qv0.w*e0.w;
        float s1 = qv1.x*e1.x + qv1.y*e1.y + qv1.z*e1.z + qv1.w*e1.w;
        float s2 = qv2.x*e2.x + qv2.y*e2.y + qv2.z*e2.z + qv2.w*e2.w;
        float s3 = qv3.x*e3.x + qv3.y*e3.y + qv3.z*e3.z + qv3.w*e3.w;
        float acc = (s0 + s1) + (s2 + s3);
        acc = wave_reduce_sum(acc);
        if (lane == 0) sim_s[a] = acc;
    }
    __syncthreads();

    if (tid >= 64) return;   // no further barriers — safe early exit

    const int a = lane;
    const float s  = sim_s[a];
    const float sc = scores[(size_t)b * A + a];

    // softmax over sim (TEMPERATURE == 1)
    const float m  = wave_reduce_max(s);
    const float ex = expf(s - m);
    const float se = wave_reduce_sum(ex);
    const float p  = ex / se;
    const float logp = logf(p + EPS);

    // target softmax over scores
    const float tm = wave_reduce_max(sc);
    const float te = expf(sc - tm);
    const float ts = wave_reduce_sum(te);
    const float t  = te / ts;
    const float logt = logf(t);

    const float kl = wave_reduce_sum(t * (logt - logp));

    // stable descending ranks: 1 + #{greater} + #{equal with lower index}
    int rp = 1, ri = 1;
    #pragma unroll
    for (int o = 0; o < 64; ++o) {
        const float so = __shfl(s,  o, 64);
        const float co = __shfl(sc, o, 64);
        rp += (so > s)  || (so == s  && o < a);
        ri += (co > sc) || (co == sc && o < a);
    }

    const float pd = wave_reduce_sum(sc / log2f((float)(rp + 1)));
    const float id = wave_reduce_sum(sc / log2f((float)(ri + 1)));

    if (lane == 0) {
        kl_out[b] = kl;
        nd_out[b] = pd / (id + EPS);
    }
}

// ---------------------------------------------------------------------------
// Reduce B per-row values -> out[0]=mean(kl), out[1]=mean(ndcg)
// ---------------------------------------------------------------------------
__global__ __launch_bounds__(256) void final_kernel(
    const float* __restrict__ kl_in, const float* __restrict__ nd_in,
    float* __restrict__ out)
{
    const int tid  = threadIdx.x;
    const int wave = tid >> 6;
    const int lane = tid & 63;
    __shared__ float sk[4], sn[4];

    float kl = 0.f, nd = 0.f;
    for (int i = tid; i < B; i += 256) {
        kl += kl_in[i];
        nd += nd_in[i];
    }
    kl = wave_reduce_sum(kl);
    nd = wave_reduce_sum(nd);
    if (lane == 0) { sk[wave] = kl; sn[wave] = nd; }
    __syncthreads();
    if (tid == 0) {
        out[0] = (sk[0] + sk[1] + sk[2] + sk[3]) * (1.0f / B);
        out[1] = (sn[0] + sn[1] + sn[2] + sn[3]) * (1.0f / B);
    }
}

extern "C" void kernel_launch(void* const* d_in, const int* in_sizes, int n_in,
                              void* d_out, int out_size, void* d_ws, size_t ws_size,
                              hipStream_t stream) {
    const float* q      = (const float*)d_in[0];  // [B, D]
    const float* emb    = (const float*)d_in[1];  // [B, A, D]
    const float* scores = (const float*)d_in[2];  // [B, A]
    float* out = (float*)d_out;                   // [2]

    float* kl_b = (float*)d_ws;   // [B]
    float* nd_b = kl_b + B;       // [B]

    rank_fused  <<<B, 256, 0, stream>>>(q, emb, scores, kl_b, nd_b);
    final_kernel<<<1, 256, 0, stream>>>(kl_b, nd_b, out);
}